// Round 7
// baseline (1174.008 us; speedup 1.0000x reference)
//
#include <hip/hip_runtime.h>
#include <math.h>
#include <stdint.h>

// MultiHeadAttention: B=2,S=2048,D=768,H=12,depth=64
// out = (softmax(mask(QK^T/8)) V) Wo^T + bo ; also returns attn itself.
// d_out = [out (B*S*D) | attn (B*H*S*S)] fp32.
//
// Round 6 design (resubmitted after broker timeout): round-5's fusion kept,
// parallelism restored.
//  scores_tile (6144 blocks): raw masked/scaled scores + PER-K-TILE partial
//    (max,sum) stats -> pstat.
//  stat_combine (192 blocks): fold 16 partials/row -> mstat (m, 1/sum).
//  pv_fused2 (1536 blocks, barrier-free K loop): normalize in place (writes
//    attn), PV MFMA with V read straight from L2 (no LDS staging, no barriers
//    until the final kt-half combine).
constexpr int B_ = 2, S_ = 2048, D_ = 768, H_ = 12, DP_ = 64;
constexpr int M_ = B_ * S_;                              // 4096 rows
constexpr size_t HS_ELEMS = (size_t)B_ * H_ * S_ * DP_;  // head-split tensor elems
constexpr size_t OUT_ELEMS = (size_t)M_ * D_;
constexpr size_t NROWS = (size_t)B_ * H_ * S_;           // attn row count (49152)
constexpr int NKT = 16;                                  // 128-key tiles per row
constexpr size_t PSTRIDE = (size_t)NKT * NROWS;          // pstat plane stride

typedef __bf16 bf16_t;
typedef bf16_t bf16x8 __attribute__((ext_vector_type(8)));
typedef float f32x4 __attribute__((ext_vector_type(4)));

__device__ __forceinline__ f32x4 mfma16(bf16x8 a, bf16x8 b, f32x4 c) {
  return __builtin_amdgcn_mfma_f32_16x16x32_bf16(a, b, c, 0, 0, 0);
}

__device__ __forceinline__ float truncbf(float x) {
  return __uint_as_float(__float_as_uint(x) & 0xFFFF0000u);
}
__device__ __forceinline__ uint32_t pack_hi2(float x, float y) {
  return (__float_as_uint(x) >> 16) | (__float_as_uint(y) & 0xFFFF0000u);
}
__device__ __forceinline__ uint32_t pack_lo2(float x, float y) {
  const float lx = x - truncbf(x);   // exact (Sterbenz)
  const float ly = y - truncbf(y);
  return (__float_as_uint(lx) >> 16) | (__float_as_uint(ly) & 0xFFFF0000u);
}
// 8 consecutive floats -> hi/lo planes, packed 2 bf16 per uint.
__device__ __forceinline__ void cvt8(const float4 a, const float4 b, uint4& H, uint4& L) {
  H.x = pack_hi2(a.x, a.y); H.y = pack_hi2(a.z, a.w);
  H.z = pack_hi2(b.x, b.y); H.w = pack_hi2(b.z, b.w);
  L.x = pack_lo2(a.x, a.y); L.y = pack_lo2(a.z, a.w);
  L.z = pack_lo2(b.x, b.y); L.w = pack_lo2(b.z, b.w);
}

// LDS tiles are [rows][64] bf16 (128B rows = 8 slots of 16B). Slot index is
// XOR-swizzled by (row&7): conflict-free ds_read_b128 fragment loads (T2/G4).
__device__ __forceinline__ bf16x8 ldfrag(const uint16_t (*T)[64], int row, int slot) {
  return *(const bf16x8*)&T[row][(slot ^ (row & 7)) << 3];
}

// ---------------------------------------------------------------------------
// Projections  Y = X @ W^T + bias.  X:[M,768], W:[768,768], both K-contiguous.
// 128x128 tile, BK=64, 256 threads = 4 waves (2x2 of 64x64), split-bf16 MFMA.
// MODE: 0 flat [M,768]; 1 headsplit [B,H,S,64]; 2 headsplit-transposed [B,H,64,S]
// (unchanged from round 5 — verified)
// ---------------------------------------------------------------------------
template <int MODE>
__global__ __launch_bounds__(256) void xwt_mfma(const float* __restrict__ X,
                                                const float* __restrict__ W,
                                                const float* __restrict__ bias,
                                                float* __restrict__ Y) {
  __shared__ alignas(16) uint16_t Xh[128][64], Xl[128][64], Wh[128][64], Wl[128][64];
  const float* Xb = X + (size_t)blockIdx.x * 128 * D_;
  const float* Wb = W + (size_t)blockIdx.y * 128 * D_;
  const int t = threadIdx.x;
  const int lane = t & 63, wid = t >> 6;
  const int wm = (wid >> 1) * 64, wn = (wid & 1) * 64;
  const int r = lane & 15, g = lane >> 4;
  f32x4 acc[4][4] = {};
  for (int k0 = 0; k0 < D_; k0 += 64) {
    __syncthreads();  // protect previous iteration's fragment reads
#pragma unroll
    for (int i = 0; i < 8; ++i) {
      const int u = t + i * 256;
      const int tens = u >> 10;  // 0 = X, 1 = W (uniform per unrolled i)
      const int idx = u & 1023;
      const int row = idx >> 3, sl = idx & 7;
      const float* src = (tens ? Wb : Xb) + (size_t)row * D_ + k0 + sl * 8;
      const float4 a = *(const float4*)src;
      const float4 b = *(const float4*)(src + 4);
      uint4 H, L; cvt8(a, b, H, L);
      const int ps = (sl ^ (row & 7)) << 3;
      if (tens) { *(uint4*)&Wh[row][ps] = H; *(uint4*)&Wl[row][ps] = L; }
      else      { *(uint4*)&Xh[row][ps] = H; *(uint4*)&Xl[row][ps] = L; }
    }
    __syncthreads();
#pragma unroll
    for (int ks = 0; ks < 2; ++ks) {
      const int slot = ks * 4 + g;
      bf16x8 aH[4], aL[4], bH[4], bL[4];
#pragma unroll
      for (int mi = 0; mi < 4; ++mi) {
        const int row = wm + mi * 16 + r;
        aH[mi] = ldfrag(Xh, row, slot); aL[mi] = ldfrag(Xl, row, slot);
      }
#pragma unroll
      for (int ni = 0; ni < 4; ++ni) {
        const int row = wn + ni * 16 + r;
        bH[ni] = ldfrag(Wh, row, slot); bL[ni] = ldfrag(Wl, row, slot);
      }
#pragma unroll
      for (int mi = 0; mi < 4; ++mi)
#pragma unroll
        for (int ni = 0; ni < 4; ++ni) {
          acc[mi][ni] = mfma16(aH[mi], bH[ni], acc[mi][ni]);
          acc[mi][ni] = mfma16(aH[mi], bL[ni], acc[mi][ni]);
          acc[mi][ni] = mfma16(aL[mi], bH[ni], acc[mi][ni]);
        }
    }
  }
  const int m0 = blockIdx.x * 128 + wm;
  const int n0 = blockIdx.y * 128 + wn;
#pragma unroll
  for (int mi = 0; mi < 4; ++mi) {
    const int rowb = m0 + mi * 16 + 4 * g;  // + j
#pragma unroll
    for (int ni = 0; ni < 4; ++ni) {
      const int col = n0 + ni * 16 + r;
      const float bv = bias[col];
      if (MODE == 0) {
        float* dst = Y + (size_t)rowb * D_ + col;
#pragma unroll
        for (int j = 0; j < 4; ++j) dst[(size_t)j * D_] = acc[mi][ni][j] + bv;
      } else if (MODE == 1) {
        const int h = col >> 6, d = col & 63;
#pragma unroll
        for (int j = 0; j < 4; ++j) {
          const int m = rowb + j;
          const int b = m >> 11, s = m & (S_ - 1);
          Y[(((size_t)b * H_ + h) * S_ + s) * DP_ + d] = acc[mi][ni][j] + bv;
        }
      } else {  // MODE 2: Vt[b][h][d][s] — 4 consecutive s => float4
        const int h = col >> 6, d = col & 63;
        const int b = rowb >> 11, s = rowb & (S_ - 1);
        float4 o;
        o.x = acc[mi][ni][0] + bv; o.y = acc[mi][ni][1] + bv;
        o.z = acc[mi][ni][2] + bv; o.w = acc[mi][ni][3] + bv;
        *(float4*)(Y + (((size_t)b * H_ + h) * DP_ + d) * S_ + s) = o;
      }
    }
  }
}

// ---------------------------------------------------------------------------
// scores_tile: grid (qtile=16, ktile=16, bh=24) — 6144 blocks, full occupancy.
// Per block: 128x128 masked/scaled raw score tile (written to attn buffer) +
// per-row PARTIAL (max, sum) over this tile's 128 keys -> pstat[ktile].
// Masked entries: -1e30 score, 0 contribution to sum.
// ---------------------------------------------------------------------------
__global__ __launch_bounds__(256) void scores_tile(const float* __restrict__ Q,
                                                   const float* __restrict__ K,
                                                   const int* __restrict__ mask,
                                                   float* __restrict__ P,
                                                   float* __restrict__ pstat) {
  __shared__ alignas(16) uint16_t Qh[128][64], Ql[128][64], Kh[128][64], Kl[128][64];
  __shared__ float mred[2][2][64], sred[2][2][64];
  const int bh = blockIdx.z;
  const int qbase = blockIdx.x * 128, kbase = blockIdx.y * 128;
  const float* Qb = Q + ((size_t)bh * S_ + qbase) * DP_;
  const float* Kb = K + ((size_t)bh * S_ + kbase) * DP_;
  float* Pb = P + ((size_t)bh * S_ + qbase) * S_ + kbase;
  const int* mb = mask + (size_t)(bh / H_) * S_ + kbase;
  const int t = threadIdx.x;
#pragma unroll
  for (int i = 0; i < 8; ++i) {
    const int u = t + i * 256;
    const int tens = u >> 10;  // 0 = Q, 1 = K
    const int idx = u & 1023;
    const int row = idx >> 3, sl = idx & 7;
    const float* src = (tens ? Kb : Qb) + (size_t)row * DP_ + sl * 8;
    const float4 a = *(const float4*)src;
    const float4 b = *(const float4*)(src + 4);
    uint4 H, L; cvt8(a, b, H, L);
    const int ps = (sl ^ (row & 7)) << 3;
    if (tens) { *(uint4*)&Kh[row][ps] = H; *(uint4*)&Kl[row][ps] = L; }
    else      { *(uint4*)&Qh[row][ps] = H; *(uint4*)&Ql[row][ps] = L; }
  }
  __syncthreads();
  const int lane = t & 63, wid = t >> 6;
  const int wm = (wid >> 1) * 64, wn = (wid & 1) * 64;
  const int r = lane & 15, g = lane >> 4;
  f32x4 acc[4][4] = {};
#pragma unroll
  for (int ks = 0; ks < 2; ++ks) {
    const int slot = ks * 4 + g;
    bf16x8 aH[4], aL[4], bH[4], bL[4];
#pragma unroll
    for (int mi = 0; mi < 4; ++mi) {
      const int row = wm + mi * 16 + r;
      aH[mi] = ldfrag(Qh, row, slot); aL[mi] = ldfrag(Ql, row, slot);
    }
#pragma unroll
    for (int ni = 0; ni < 4; ++ni) {
      const int row = wn + ni * 16 + r;
      bH[ni] = ldfrag(Kh, row, slot); bL[ni] = ldfrag(Kl, row, slot);
    }
#pragma unroll
    for (int mi = 0; mi < 4; ++mi)
#pragma unroll
      for (int ni = 0; ni < 4; ++ni) {
        acc[mi][ni] = mfma16(aH[mi], bH[ni], acc[mi][ni]);
        acc[mi][ni] = mfma16(aH[mi], bL[ni], acc[mi][ni]);
        acc[mi][ni] = mfma16(aL[mi], bH[ni], acc[mi][ni]);
      }
  }
  // mask + scale + write raw + per-(row, this 128-key tile) partial stats
  int msk[4];
#pragma unroll
  for (int ni = 0; ni < 4; ++ni) msk[ni] = mb[wn + ni * 16 + r];
  float m_[4][4], s_[4][4];
#pragma unroll
  for (int mi = 0; mi < 4; ++mi) {
    float tv[4][4];
#pragma unroll
    for (int ni = 0; ni < 4; ++ni)
#pragma unroll
      for (int j = 0; j < 4; ++j) {
        const float sv = msk[ni] ? acc[mi][ni][j] * 0.125f : -1e30f;
        tv[ni][j] = sv;
        Pb[(size_t)(wm + mi * 16 + 4 * g + j) * S_ + wn + ni * 16 + r] = sv;
      }
#pragma unroll
    for (int j = 0; j < 4; ++j) {
      const float pm = fmaxf(fmaxf(tv[0][j], tv[1][j]), fmaxf(tv[2][j], tv[3][j]));
      float ps = 0.f;
#pragma unroll
      for (int ni = 0; ni < 4; ++ni)
        ps += (tv[ni][j] <= -1e29f) ? 0.f : __expf(tv[ni][j] - pm);
      m_[mi][j] = pm; s_[mi][j] = ps;
    }
  }
  // combine across the 16 r-lanes (different keys, same q-row)
#pragma unroll
  for (int off = 1; off < 16; off <<= 1) {
#pragma unroll
    for (int mi = 0; mi < 4; ++mi)
#pragma unroll
      for (int j = 0; j < 4; ++j) {
        const float om = __shfl_xor(m_[mi][j], off);
        const float os = __shfl_xor(s_[mi][j], off);
        const float mn = fmaxf(m_[mi][j], om);
        s_[mi][j] = s_[mi][j] * __expf(m_[mi][j] - mn) + os * __expf(om - mn);
        m_[mi][j] = mn;
      }
  }
  // combine the two wn-half waves via LDS, then write this k-tile's partials
  if (r == 0) {
#pragma unroll
    for (int mi = 0; mi < 4; ++mi)
#pragma unroll
      for (int j = 0; j < 4; ++j) {
        mred[wid >> 1][wid & 1][mi * 16 + 4 * g + j] = m_[mi][j];
        sred[wid >> 1][wid & 1][mi * 16 + 4 * g + j] = s_[mi][j];
      }
  }
  __syncthreads();
  if (t < 128) {
    const int half = t >> 6, rowid = t & 63;
    const float m0 = mred[half][0][rowid], m1 = mred[half][1][rowid];
    const float s0 = sred[half][0][rowid], s1 = sred[half][1][rowid];
    const float mn = fmaxf(m0, m1);
    const float s = s0 * __expf(m0 - mn) + s1 * __expf(m1 - mn);
    const size_t row = (size_t)bh * S_ + qbase + half * 64 + rowid;
    pstat[(size_t)blockIdx.y * NROWS + row] = mn;
    pstat[PSTRIDE + (size_t)blockIdx.y * NROWS + row] = s;
  }
}

// ---------------------------------------------------------------------------
// stat_combine: one thread per q-row; fold 16 per-tile partials -> (m, 1/sum).
// ---------------------------------------------------------------------------
__global__ __launch_bounds__(256) void stat_combine(const float* __restrict__ pstat,
                                                    float* __restrict__ mstat) {
  const size_t row = (size_t)blockIdx.x * 256 + threadIdx.x;  // NROWS = 192*256
  float m = pstat[row], s = pstat[PSTRIDE + row];
#pragma unroll
  for (int kt = 1; kt < NKT; ++kt) {
    const float pm = pstat[(size_t)kt * NROWS + row];
    const float ps = pstat[PSTRIDE + (size_t)kt * NROWS + row];
    const float mn = fmaxf(m, pm);
    s = s * __expf(m - mn) + ps * __expf(pm - mn);
    m = mn;
  }
  mstat[row] = m;
  mstat[NROWS + row] = 1.0f / s;
}

// ---------------------------------------------------------------------------
// pv_fused2: grid (S/32=64, B*H=24) = 1536 blocks, 4 waves = (qg 2) x (kh 2).
// Wave (qg,kh): 16 q-rows (qbase+qg*16..), keys kh*1024..+1024 — fully
// independent, BARRIER-FREE main loop. Per-lane stats from global; V fragments
// read straight from L2-resident Vt (no LDS staging). Normalized attn written
// in place. Final: kh=1 wave dumps acc to LDS, one barrier, kh=0 adds + writes
// ctx concat layout [B,S,768].
// ---------------------------------------------------------------------------
__global__ __launch_bounds__(256) void pv_fused2(float* __restrict__ P,
                                                 const float* __restrict__ Vt,
                                                 const float* __restrict__ mstat,
                                                 float* __restrict__ C) {
  __shared__ float ored[2][16][64];  // 8 KB: kt-half combine buffer
  const int bh = blockIdx.y;
  const int b = bh / H_, h = bh % H_;
  const int qbase = blockIdx.x * 32;
  float* Pb = P + ((size_t)bh * S_ + qbase) * S_;
  const float* Vb = Vt + (size_t)bh * DP_ * S_;
  const int t = threadIdx.x;
  const int lane = t & 63, wid = t >> 6;
  const int qg = wid >> 1, kh = wid & 1;
  const int r = lane & 15, g = lane >> 4;
  const int qloc = qg * 16 + r;  // P-row this lane reads/normalizes
  const size_t qglob = (size_t)bh * S_ + qbase + qloc;
  const float mq = mstat[qglob];
  const float iv = mstat[NROWS + qglob];
  float* Prow = Pb + (size_t)qloc * S_;
  f32x4 acc[4] = {};
  for (int kt2 = 0; kt2 < 16; ++kt2) {
    const int kt = kh * 16 + kt2;
#pragma unroll
    for (int ks = 0; ks < 2; ++ks) {
      const int koff = kt * 64 + (ks * 4 + g) * 8;
      float* src = Prow + koff;
      float4 p0 = *(const float4*)src;
      float4 p1 = *(const float4*)(src + 4);
      p0.x = __expf(p0.x - mq) * iv; p0.y = __expf(p0.y - mq) * iv;
      p0.z = __expf(p0.z - mq) * iv; p0.w = __expf(p0.w - mq) * iv;
      p1.x = __expf(p1.x - mq) * iv; p1.y = __expf(p1.y - mq) * iv;
      p1.z = __expf(p1.z - mq) * iv; p1.w = __expf(p1.w - mq) * iv;
      *(float4*)src = p0;             // normalized attn, in place
      *(float4*)(src + 4) = p1;
      uint4 AH, AL; cvt8(p0, p1, AH, AL);
      const bf16x8 aH = *(bf16x8*)&AH, aL = *(bf16x8*)&AL;
#pragma unroll
      for (int ni = 0; ni < 4; ++ni) {
        const float* vsrc = Vb + (size_t)(ni * 16 + r) * S_ + koff;
        const float4 v0 = *(const float4*)vsrc;
        const float4 v1 = *(const float4*)(vsrc + 4);
        uint4 BH, BL; cvt8(v0, v1, BH, BL);
        const bf16x8 bH = *(bf16x8*)&BH, bL = *(bf16x8*)&BL;
        acc[ni] = mfma16(aH, bH, acc[ni]);
        acc[ni] = mfma16(aH, bL, acc[ni]);
        acc[ni] = mfma16(aL, bH, acc[ni]);
      }
    }
  }
  // combine kt-halves: kh=1 -> LDS; kh=0 adds and writes ctx.
  if (kh == 1) {
#pragma unroll
    for (int ni = 0; ni < 4; ++ni)
#pragma unroll
      for (int j = 0; j < 4; ++j)
        ored[qg][4 * g + j][ni * 16 + r] = acc[ni][j];
  }
  __syncthreads();
  if (kh == 0) {
#pragma unroll
    for (int ni = 0; ni < 4; ++ni) {
      const int d = ni * 16 + r;
#pragma unroll
      for (int j = 0; j < 4; ++j) {
        const float o = acc[ni][j] + ored[qg][4 * g + j][d];
        const int q = qbase + qg * 16 + 4 * g + j;
        C[(size_t)(b * S_ + q) * D_ + h * DP_ + d] = o;
      }
    }
  }
}

extern "C" void kernel_launch(void* const* d_in, const int* in_sizes, int n_in,
                              void* d_out, int out_size, void* d_ws, size_t ws_size,
                              hipStream_t stream) {
  (void)in_sizes; (void)n_in; (void)out_size; (void)ws_size;
  const float* q = (const float*)d_in[0];
  const float* k = (const float*)d_in[1];
  const float* v = (const float*)d_in[2];
  const int* mask = (const int*)d_in[3];
  const float* wq_w = (const float*)d_in[4];
  const float* wq_b = (const float*)d_in[5];
  const float* wk_w = (const float*)d_in[6];
  const float* wk_b = (const float*)d_in[7];
  const float* wv_w = (const float*)d_in[8];
  const float* wv_b = (const float*)d_in[9];
  const float* wo_w = (const float*)d_in[10];
  const float* wo_b = (const float*)d_in[11];

  float* out = (float*)d_out;
  float* attn = (float*)d_out + OUT_ELEMS;

  float* qh = (float*)d_ws;            // [B,H,S,64]
  float* kh = qh + HS_ELEMS;           // [B,H,S,64]
  float* vt = kh + HS_ELEMS;           // [B,H,64,S] (transposed V)
  float* ctx = vt + HS_ELEMS;          // [B,S,768] concat layout
  float* mstat = ctx + OUT_ELEMS;      // [2][NROWS] rowmax, 1/rowsum
  float* pstat = mstat + 2 * NROWS;    // [2][16][NROWS] per-ktile partials

  const dim3 gproj(M_ / 128, D_ / 128);
  xwt_mfma<1><<<gproj, 256, 0, stream>>>(q, wq_w, wq_b, qh);
  xwt_mfma<1><<<gproj, 256, 0, stream>>>(k, wk_w, wk_b, kh);
  xwt_mfma<2><<<gproj, 256, 0, stream>>>(v, wv_w, wv_b, vt);

  const dim3 gsc(S_ / 128, S_ / 128, B_ * H_);
  scores_tile<<<gsc, 256, 0, stream>>>(qh, kh, mask, attn, pstat);

  stat_combine<<<dim3(NROWS / 256), 256, 0, stream>>>(pstat, mstat);

  const dim3 gpv(S_ / 32, B_ * H_);
  pv_fused2<<<gpv, 256, 0, stream>>>(attn, vt, mstat, ctx);

  xwt_mfma<0><<<gproj, 256, 0, stream>>>(ctx, wo_w, wo_b, out);
}

// Round 10
// 1076.949 us; speedup vs baseline: 1.0901x; 1.0901x over previous
//
#include <hip/hip_runtime.h>
#include <math.h>
#include <stdint.h>

// MultiHeadAttention: B=2,S=2048,D=768,H=12,depth=64
// out = (softmax(mask(QK^T/8)) V) Wo^T + bo ; also returns attn itself.
// d_out = [out (B*S*D) | attn (B*H*S*S)] fp32.
//
// Round 8 design (resubmitted again after broker timeouts): round-7
// structure, latency fixed.
//  - pv_fused3: software-pipelined (double-buffered prefetch) K loop; V read
//    as precomputed split-bf16 planes (no per-use cvt). Convoy stall killed.
//  - xwt_mfma MODE 2 writes Vt as two bf16 planes (exact hi/lo split).
//  - scores_tile: stats via max-butterfly -> single exp pass -> sum-butterfly
//    (64 exp/thread instead of 192).
constexpr int B_ = 2, S_ = 2048, D_ = 768, H_ = 12, DP_ = 64;
constexpr int M_ = B_ * S_;                              // 4096 rows
constexpr size_t HS_ELEMS = (size_t)B_ * H_ * S_ * DP_;  // head-split tensor elems
constexpr size_t OUT_ELEMS = (size_t)M_ * D_;
constexpr size_t NROWS = (size_t)B_ * H_ * S_;           // attn row count (49152)
constexpr int NKT = 16;                                  // 128-key tiles per row
constexpr size_t PSTRIDE = (size_t)NKT * NROWS;          // pstat plane stride

typedef __bf16 bf16_t;
typedef bf16_t bf16x8 __attribute__((ext_vector_type(8)));
typedef float f32x4 __attribute__((ext_vector_type(4)));

__device__ __forceinline__ f32x4 mfma16(bf16x8 a, bf16x8 b, f32x4 c) {
  return __builtin_amdgcn_mfma_f32_16x16x32_bf16(a, b, c, 0, 0, 0);
}

__device__ __forceinline__ float truncbf(float x) {
  return __uint_as_float(__float_as_uint(x) & 0xFFFF0000u);
}
__device__ __forceinline__ uint32_t pack_hi2(float x, float y) {
  return (__float_as_uint(x) >> 16) | (__float_as_uint(y) & 0xFFFF0000u);
}
__device__ __forceinline__ uint32_t pack_lo2(float x, float y) {
  const float lx = x - truncbf(x);   // exact (Sterbenz)
  const float ly = y - truncbf(y);
  return (__float_as_uint(lx) >> 16) | (__float_as_uint(ly) & 0xFFFF0000u);
}
// 8 consecutive floats -> hi/lo planes, packed 2 bf16 per uint.
__device__ __forceinline__ void cvt8(const float4 a, const float4 b, uint4& H, uint4& L) {
  H.x = pack_hi2(a.x, a.y); H.y = pack_hi2(a.z, a.w);
  H.z = pack_hi2(b.x, b.y); H.w = pack_hi2(b.z, b.w);
  L.x = pack_lo2(a.x, a.y); L.y = pack_lo2(a.z, a.w);
  L.z = pack_lo2(b.x, b.y); L.w = pack_lo2(b.z, b.w);
}

// LDS tiles are [rows][64] bf16 (128B rows = 8 slots of 16B). Slot index is
// XOR-swizzled by (row&7): conflict-free ds_read_b128 fragment loads (T2/G4).
__device__ __forceinline__ bf16x8 ldfrag(const uint16_t (*T)[64], int row, int slot) {
  return *(const bf16x8*)&T[row][(slot ^ (row & 7)) << 3];
}

// ---------------------------------------------------------------------------
// Projections  Y = X @ W^T + bias.  X:[M,768], W:[768,768], both K-contiguous.
// 128x128 tile, BK=64, 256 threads = 4 waves (2x2 of 64x64), split-bf16 MFMA.
// MODE: 0 flat [M,768]; 1 headsplit [B,H,S,64];
//       2 headsplit-transposed split-bf16 planes Yh/Yl: [B,H,64,S] uint16.
// ---------------------------------------------------------------------------
template <int MODE>
__global__ __launch_bounds__(256) void xwt_mfma(const float* __restrict__ X,
                                                const float* __restrict__ W,
                                                const float* __restrict__ bias,
                                                float* __restrict__ Y,
                                                uint16_t* __restrict__ Yh,
                                                uint16_t* __restrict__ Yl) {
  __shared__ alignas(16) uint16_t Xh[128][64], Xl[128][64], Wh[128][64], Wl[128][64];
  const float* Xb = X + (size_t)blockIdx.x * 128 * D_;
  const float* Wb = W + (size_t)blockIdx.y * 128 * D_;
  const int t = threadIdx.x;
  const int lane = t & 63, wid = t >> 6;
  const int wm = (wid >> 1) * 64, wn = (wid & 1) * 64;
  const int r = lane & 15, g = lane >> 4;
  f32x4 acc[4][4] = {};
  for (int k0 = 0; k0 < D_; k0 += 64) {
    __syncthreads();  // protect previous iteration's fragment reads
#pragma unroll
    for (int i = 0; i < 8; ++i) {
      const int u = t + i * 256;
      const int tens = u >> 10;  // 0 = X, 1 = W (uniform per unrolled i)
      const int idx = u & 1023;
      const int row = idx >> 3, sl = idx & 7;
      const float* src = (tens ? Wb : Xb) + (size_t)row * D_ + k0 + sl * 8;
      const float4 a = *(const float4*)src;
      const float4 b = *(const float4*)(src + 4);
      uint4 H, L; cvt8(a, b, H, L);
      const int ps = (sl ^ (row & 7)) << 3;
      if (tens) { *(uint4*)&Wh[row][ps] = H; *(uint4*)&Wl[row][ps] = L; }
      else      { *(uint4*)&Xh[row][ps] = H; *(uint4*)&Xl[row][ps] = L; }
    }
    __syncthreads();
#pragma unroll
    for (int ks = 0; ks < 2; ++ks) {
      const int slot = ks * 4 + g;
      bf16x8 aH[4], aL[4], bH[4], bL[4];
#pragma unroll
      for (int mi = 0; mi < 4; ++mi) {
        const int row = wm + mi * 16 + r;
        aH[mi] = ldfrag(Xh, row, slot); aL[mi] = ldfrag(Xl, row, slot);
      }
#pragma unroll
      for (int ni = 0; ni < 4; ++ni) {
        const int row = wn + ni * 16 + r;
        bH[ni] = ldfrag(Wh, row, slot); bL[ni] = ldfrag(Wl, row, slot);
      }
#pragma unroll
      for (int mi = 0; mi < 4; ++mi)
#pragma unroll
        for (int ni = 0; ni < 4; ++ni) {
          acc[mi][ni] = mfma16(aH[mi], bH[ni], acc[mi][ni]);
          acc[mi][ni] = mfma16(aH[mi], bL[ni], acc[mi][ni]);
          acc[mi][ni] = mfma16(aL[mi], bH[ni], acc[mi][ni]);
        }
    }
  }
  const int m0 = blockIdx.x * 128 + wm;
  const int n0 = blockIdx.y * 128 + wn;
#pragma unroll
  for (int mi = 0; mi < 4; ++mi) {
    const int rowb = m0 + mi * 16 + 4 * g;  // + j
#pragma unroll
    for (int ni = 0; ni < 4; ++ni) {
      const int col = n0 + ni * 16 + r;
      const float bv = bias[col];
      if (MODE == 0) {
        float* dst = Y + (size_t)rowb * D_ + col;
#pragma unroll
        for (int j = 0; j < 4; ++j) dst[(size_t)j * D_] = acc[mi][ni][j] + bv;
      } else if (MODE == 1) {
        const int h = col >> 6, d = col & 63;
#pragma unroll
        for (int j = 0; j < 4; ++j) {
          const int m = rowb + j;
          const int b = m >> 11, s = m & (S_ - 1);
          Y[(((size_t)b * H_ + h) * S_ + s) * DP_ + d] = acc[mi][ni][j] + bv;
        }
      } else {  // MODE 2: split-bf16 Vt planes [B,H,64,S], 4 consecutive s
        const int h = col >> 6, d = col & 63;
        const int b = rowb >> 11, s = rowb & (S_ - 1);
        const float o0 = acc[mi][ni][0] + bv, o1 = acc[mi][ni][1] + bv;
        const float o2 = acc[mi][ni][2] + bv, o3 = acc[mi][ni][3] + bv;
        uint2 hi, lo;
        hi.x = pack_hi2(o0, o1); hi.y = pack_hi2(o2, o3);
        lo.x = pack_lo2(o0, o1); lo.y = pack_lo2(o2, o3);
        const size_t off = (((size_t)b * H_ + h) * DP_ + d) * S_ + s;
        *(uint2*)(Yh + off) = hi;
        *(uint2*)(Yl + off) = lo;
      }
    }
  }
}

// ---------------------------------------------------------------------------
// scores_tile: grid (qtile=16, ktile=16, bh=24) — 6144 blocks.
// Per block: 128x128 masked/scaled raw score tile (written to attn buffer) +
// per-row PARTIAL (max, sum) over this tile's 128 keys -> pstat[ktile].
// Stats: max-butterfly first, ONE exp pass vs tile max, sum-butterfly
// (64 exp/thread vs 192 in the online variant).
// ---------------------------------------------------------------------------
__global__ __launch_bounds__(256) void scores_tile(const float* __restrict__ Q,
                                                   const float* __restrict__ K,
                                                   const int* __restrict__ mask,
                                                   float* __restrict__ P,
                                                   float* __restrict__ pstat) {
  __shared__ alignas(16) uint16_t Qh[128][64], Ql[128][64], Kh[128][64], Kl[128][64];
  __shared__ float mred[2][2][64], sred[2][2][64];
  const int bh = blockIdx.z;
  const int qbase = blockIdx.x * 128, kbase = blockIdx.y * 128;
  const float* Qb = Q + ((size_t)bh * S_ + qbase) * DP_;
  const float* Kb = K + ((size_t)bh * S_ + kbase) * DP_;
  float* Pb = P + ((size_t)bh * S_ + qbase) * S_ + kbase;
  const int* mb = mask + (size_t)(bh / H_) * S_ + kbase;
  const int t = threadIdx.x;
#pragma unroll
  for (int i = 0; i < 8; ++i) {
    const int u = t + i * 256;
    const int tens = u >> 10;  // 0 = Q, 1 = K
    const int idx = u & 1023;
    const int row = idx >> 3, sl = idx & 7;
    const float* src = (tens ? Kb : Qb) + (size_t)row * DP_ + sl * 8;
    const float4 a = *(const float4*)src;
    const float4 b = *(const float4*)(src + 4);
    uint4 H, L; cvt8(a, b, H, L);
    const int ps = (sl ^ (row & 7)) << 3;
    if (tens) { *(uint4*)&Kh[row][ps] = H; *(uint4*)&Kl[row][ps] = L; }
    else      { *(uint4*)&Qh[row][ps] = H; *(uint4*)&Ql[row][ps] = L; }
  }
  __syncthreads();
  const int lane = t & 63, wid = t >> 6;
  const int wm = (wid >> 1) * 64, wn = (wid & 1) * 64;
  const int r = lane & 15, g = lane >> 4;
  f32x4 acc[4][4] = {};
#pragma unroll
  for (int ks = 0; ks < 2; ++ks) {
    const int slot = ks * 4 + g;
    bf16x8 aH[4], aL[4], bH[4], bL[4];
#pragma unroll
    for (int mi = 0; mi < 4; ++mi) {
      const int row = wm + mi * 16 + r;
      aH[mi] = ldfrag(Qh, row, slot); aL[mi] = ldfrag(Ql, row, slot);
    }
#pragma unroll
    for (int ni = 0; ni < 4; ++ni) {
      const int row = wn + ni * 16 + r;
      bH[ni] = ldfrag(Kh, row, slot); bL[ni] = ldfrag(Kl, row, slot);
    }
#pragma unroll
    for (int mi = 0; mi < 4; ++mi)
#pragma unroll
      for (int ni = 0; ni < 4; ++ni) {
        acc[mi][ni] = mfma16(aH[mi], bH[ni], acc[mi][ni]);
        acc[mi][ni] = mfma16(aH[mi], bL[ni], acc[mi][ni]);
        acc[mi][ni] = mfma16(aL[mi], bH[ni], acc[mi][ni]);
      }
  }
  // mask + scale + write raw + per-(row, this 128-key tile) partial stats
  int msk[4];
#pragma unroll
  for (int ni = 0; ni < 4; ++ni) msk[ni] = mb[wn + ni * 16 + r];
  float m_[4][4], s_[4][4];
#pragma unroll
  for (int mi = 0; mi < 4; ++mi) {
    float tv[4][4];
#pragma unroll
    for (int ni = 0; ni < 4; ++ni)
#pragma unroll
      for (int j = 0; j < 4; ++j) {
        const float sv = msk[ni] ? acc[mi][ni][j] * 0.125f : -1e30f;
        tv[ni][j] = sv;
        Pb[(size_t)(wm + mi * 16 + 4 * g + j) * S_ + wn + ni * 16 + r] = sv;
      }
#pragma unroll
    for (int j = 0; j < 4; ++j) {
      // tile-row max across this thread's 4 values, then 16 r-lanes
      float M = fmaxf(fmaxf(tv[0][j], tv[1][j]), fmaxf(tv[2][j], tv[3][j]));
#pragma unroll
      for (int off = 1; off < 16; off <<= 1) M = fmaxf(M, __shfl_xor(M, off));
      // one exp pass vs tile max, then sum across r-lanes
      float ssum = 0.f;
#pragma unroll
      for (int ni = 0; ni < 4; ++ni)
        ssum += (tv[ni][j] <= -1e29f) ? 0.f : __expf(tv[ni][j] - M);
#pragma unroll
      for (int off = 1; off < 16; off <<= 1) ssum += __shfl_xor(ssum, off);
      m_[mi][j] = M; s_[mi][j] = ssum;
    }
  }
  // combine the two wn-half waves via LDS, then write this k-tile's partials
  if (r == 0) {
#pragma unroll
    for (int mi = 0; mi < 4; ++mi)
#pragma unroll
      for (int j = 0; j < 4; ++j) {
        mred[wid >> 1][wid & 1][mi * 16 + 4 * g + j] = m_[mi][j];
        sred[wid >> 1][wid & 1][mi * 16 + 4 * g + j] = s_[mi][j];
      }
  }
  __syncthreads();
  if (t < 128) {
    const int half = t >> 6, rowid = t & 63;
    const float m0 = mred[half][0][rowid], m1 = mred[half][1][rowid];
    const float s0 = sred[half][0][rowid], s1 = sred[half][1][rowid];
    const float mn = fmaxf(m0, m1);
    const float s = s0 * __expf(m0 - mn) + s1 * __expf(m1 - mn);
    const size_t row = (size_t)bh * S_ + qbase + half * 64 + rowid;
    pstat[(size_t)blockIdx.y * NROWS + row] = mn;
    pstat[PSTRIDE + (size_t)blockIdx.y * NROWS + row] = s;
  }
}

// ---------------------------------------------------------------------------
// stat_combine: one thread per q-row; fold 16 per-tile partials -> (m, 1/sum).
// ---------------------------------------------------------------------------
__global__ __launch_bounds__(256) void stat_combine(const float* __restrict__ pstat,
                                                    float* __restrict__ mstat) {
  const size_t row = (size_t)blockIdx.x * 256 + threadIdx.x;  // NROWS = 192*256
  float m = pstat[row], s = pstat[PSTRIDE + row];
#pragma unroll
  for (int kt = 1; kt < NKT; ++kt) {
    const float pm = pstat[(size_t)kt * NROWS + row];
    const float ps = pstat[PSTRIDE + (size_t)kt * NROWS + row];
    const float mn = fmaxf(m, pm);
    s = s * __expf(m - mn) + ps * __expf(pm - mn);
    m = mn;
  }
  mstat[row] = m;
  mstat[NROWS + row] = 1.0f / s;
}

// ---------------------------------------------------------------------------
// pv_fused3: grid (S/32=64, B*H=24) = 1536 blocks, 4 waves = (qg 2) x (kh 2).
// SOFTWARE-PIPELINED: iteration i+1's loads (P 32B + 8x uint4 bf16-V) issue
// before iteration i's compute, hiding HBM/L2 latency under exp+cvt+MFMA.
// V comes from precomputed split-bf16 planes (no per-use conversion).
// Normalized attn written in place. Final kt-half combine via LDS (1 barrier).
// ---------------------------------------------------------------------------
__global__ __launch_bounds__(256) void pv_fused3(float* __restrict__ P,
                                                 const uint16_t* __restrict__ Vth,
                                                 const uint16_t* __restrict__ Vtl,
                                                 const float* __restrict__ mstat,
                                                 float* __restrict__ C) {
  __shared__ float ored[2][16][64];  // 8 KB: kt-half combine buffer
  const int bh = blockIdx.y;
  const int b = bh / H_, h = bh % H_;
  const int qbase = blockIdx.x * 32;
  float* Pb = P + ((size_t)bh * S_ + qbase) * S_;
  const int t = threadIdx.x;
  const int lane = t & 63, wid = t >> 6;
  const int qg = wid >> 1, kh = wid & 1;
  const int r = lane & 15, g = lane >> 4;
  const int qloc = qg * 16 + r;  // P-row this lane reads/normalizes
  const size_t qglob = (size_t)bh * S_ + qbase + qloc;
  const float mq = mstat[qglob];
  const float iv = mstat[NROWS + qglob];
  float* Prow = Pb + (size_t)qloc * S_;
  const uint16_t* vbh = Vth + ((size_t)bh * DP_ + r) * S_;  // + ni*16*S_ + koff
  const uint16_t* vbl = Vtl + ((size_t)bh * DP_ + r) * S_;
  f32x4 acc[4] = {};

#define PV_KOFF(it) ((kh * 16 + ((it) >> 1)) * 64 + ((((it) & 1) * 4 + g) << 3))
#define PV_LOAD(P0, P1, VH, VL, it) do {                                   \
    const int ko_ = PV_KOFF(it);                                           \
    const float* ps_ = Prow + ko_;                                         \
    P0 = *(const float4*)ps_; P1 = *(const float4*)(ps_ + 4);              \
    VH##0 = *(const uint4*)(vbh + ko_);                                    \
    VH##1 = *(const uint4*)(vbh + 16 * S_ + ko_);                          \
    VH##2 = *(const uint4*)(vbh + 32 * S_ + ko_);                          \
    VH##3 = *(const uint4*)(vbh + 48 * S_ + ko_);                          \
    VL##0 = *(const uint4*)(vbl + ko_);                                    \
    VL##1 = *(const uint4*)(vbl + 16 * S_ + ko_);                          \
    VL##2 = *(const uint4*)(vbl + 32 * S_ + ko_);                          \
    VL##3 = *(const uint4*)(vbl + 48 * S_ + ko_);                          \
  } while (0)
#define PV_COMP(P0, P1, VH, VL, it) do {                                   \
    const int ko_ = PV_KOFF(it);                                           \
    float* ps_ = Prow + ko_;                                               \
    P0.x = __expf(P0.x - mq) * iv; P0.y = __expf(P0.y - mq) * iv;          \
    P0.z = __expf(P0.z - mq) * iv; P0.w = __expf(P0.w - mq) * iv;          \
    P1.x = __expf(P1.x - mq) * iv; P1.y = __expf(P1.y - mq) * iv;          \
    P1.z = __expf(P1.z - mq) * iv; P1.w = __expf(P1.w - mq) * iv;          \
    *(float4*)ps_ = P0; *(float4*)(ps_ + 4) = P1;  /* normalized attn */   \
    uint4 AH_, AL_; cvt8(P0, P1, AH_, AL_);                                \
    const bf16x8 aH_ = *(bf16x8*)&AH_, aL_ = *(bf16x8*)&AL_;               \
    { const bf16x8 bH_ = *(const bf16x8*)&VH##0, bL_ = *(const bf16x8*)&VL##0; \
      acc[0] = mfma16(aH_, bH_, acc[0]); acc[0] = mfma16(aH_, bL_, acc[0]); \
      acc[0] = mfma16(aL_, bH_, acc[0]); }                                 \
    { const bf16x8 bH_ = *(const bf16x8*)&VH##1, bL_ = *(const bf16x8*)&VL##1; \
      acc[1] = mfma16(aH_, bH_, acc[1]); acc[1] = mfma16(aH_, bL_, acc[1]); \
      acc[1] = mfma16(aL_, bH_, acc[1]); }                                 \
    { const bf16x8 bH_ = *(const bf16x8*)&VH##2, bL_ = *(const bf16x8*)&VL##2; \
      acc[2] = mfma16(aH_, bH_, acc[2]); acc[2] = mfma16(aH_, bL_, acc[2]); \
      acc[2] = mfma16(aL_, bH_, acc[2]); }                                 \
    { const bf16x8 bH_ = *(const bf16x8*)&VH##3, bL_ = *(const bf16x8*)&VL##3; \
      acc[3] = mfma16(aH_, bH_, acc[3]); acc[3] = mfma16(aH_, bL_, acc[3]); \
      acc[3] = mfma16(aL_, bH_, acc[3]); }                                 \
  } while (0)

  float4 pA0, pA1, pB0, pB1;
  uint4 vhA0, vhA1, vhA2, vhA3, vlA0, vlA1, vlA2, vlA3;
  uint4 vhB0, vhB1, vhB2, vhB3, vlB0, vlB1, vlB2, vlB3;
  PV_LOAD(pA0, pA1, vhA, vlA, 0);
  for (int itp = 0; itp < 16; ++itp) {
    const int it0 = 2 * itp, it1 = 2 * itp + 1;
    const int it2 = (itp < 15) ? (2 * itp + 2) : 31;  // tail: redundant load
    PV_LOAD(pB0, pB1, vhB, vlB, it1);
    PV_COMP(pA0, pA1, vhA, vlA, it0);
    PV_LOAD(pA0, pA1, vhA, vlA, it2);
    PV_COMP(pB0, pB1, vhB, vlB, it1);
  }
#undef PV_KOFF
#undef PV_LOAD
#undef PV_COMP

  // combine kt-halves: kh=1 -> LDS; kh=0 adds and writes ctx.
  if (kh == 1) {
#pragma unroll
    for (int ni = 0; ni < 4; ++ni)
#pragma unroll
      for (int j = 0; j < 4; ++j)
        ored[qg][4 * g + j][ni * 16 + r] = acc[ni][j];
  }
  __syncthreads();
  if (kh == 0) {
#pragma unroll
    for (int ni = 0; ni < 4; ++ni) {
      const int d = ni * 16 + r;
#pragma unroll
      for (int j = 0; j < 4; ++j) {
        const float o = acc[ni][j] + ored[qg][4 * g + j][d];
        const int q = qbase + qg * 16 + 4 * g + j;
        C[(size_t)(b * S_ + q) * D_ + h * DP_ + d] = o;
      }
    }
  }
}

extern "C" void kernel_launch(void* const* d_in, const int* in_sizes, int n_in,
                              void* d_out, int out_size, void* d_ws, size_t ws_size,
                              hipStream_t stream) {
  (void)in_sizes; (void)n_in; (void)out_size; (void)ws_size;
  const float* q = (const float*)d_in[0];
  const float* k = (const float*)d_in[1];
  const float* v = (const float*)d_in[2];
  const int* mask = (const int*)d_in[3];
  const float* wq_w = (const float*)d_in[4];
  const float* wq_b = (const float*)d_in[5];
  const float* wk_w = (const float*)d_in[6];
  const float* wk_b = (const float*)d_in[7];
  const float* wv_w = (const float*)d_in[8];
  const float* wv_b = (const float*)d_in[9];
  const float* wo_w = (const float*)d_in[10];
  const float* wo_b = (const float*)d_in[11];

  float* out = (float*)d_out;
  float* attn = (float*)d_out + OUT_ELEMS;

  float* qh = (float*)d_ws;                       // [B,H,S,64] f32
  float* khd = qh + HS_ELEMS;                     // [B,H,S,64] f32
  uint16_t* vth = (uint16_t*)(khd + HS_ELEMS);    // [B,H,64,S] bf16 hi
  uint16_t* vtl = vth + HS_ELEMS;                 // [B,H,64,S] bf16 lo
  float* ctx = (float*)(vtl + HS_ELEMS);          // [B,S,768] concat layout
  float* mstat = ctx + OUT_ELEMS;                 // [2][NROWS] rowmax, 1/rowsum
  float* pstat = mstat + 2 * NROWS;               // [2][16][NROWS] partials

  const dim3 gproj(M_ / 128, D_ / 128);
  xwt_mfma<1><<<gproj, 256, 0, stream>>>(q, wq_w, wq_b, qh, nullptr, nullptr);
  xwt_mfma<1><<<gproj, 256, 0, stream>>>(k, wk_w, wk_b, khd, nullptr, nullptr);
  xwt_mfma<2><<<gproj, 256, 0, stream>>>(v, wv_w, wv_b, nullptr, vth, vtl);

  const dim3 gsc(S_ / 128, S_ / 128, B_ * H_);
  scores_tile<<<gsc, 256, 0, stream>>>(qh, khd, mask, attn, pstat);

  stat_combine<<<dim3(NROWS / 256), 256, 0, stream>>>(pstat, mstat);

  const dim3 gpv(S_ / 32, B_ * H_);
  pv_fused3<<<gpv, 256, 0, stream>>>(attn, vth, vtl, mstat, ctx);

  xwt_mfma<0><<<gproj, 256, 0, stream>>>(ctx, wo_w, wo_b, out, nullptr, nullptr);
}

// Round 11
// 941.212 us; speedup vs baseline: 1.2473x; 1.1442x over previous
//
#include <hip/hip_runtime.h>
#include <math.h>
#include <stdint.h>

// MultiHeadAttention: B=2,S=2048,D=768,H=12,depth=64
// out = (softmax(mask(QK^T/8)) V) Wo^T + bo ; also returns attn itself.
// d_out = [out (B*S*D) | attn (B*H*S*S)] fp32.
//
// Round 11: fusion moved into the COALESCED round-1 ctx structure.
//  - scores_tile (6144 blocks, verified): raw masked/scaled scores +
//    per-k-tile partial (max,sum) -> pstat.
//  - stat_combine (verified): fold partials -> (m, 1/sum).
//  - ctx_fused: round-1 ctx_mfma tile structure (64x64, LDS-staged, block-
//    coalesced loads) with exp*inv applied during P staging; writes
//    normalized attn in place and ctx via split-bf16 MFMA against
//    precomputed bf16 V planes. Replaces normalize pass + pv kernel.
constexpr int B_ = 2, S_ = 2048, D_ = 768, H_ = 12, DP_ = 64;
constexpr int M_ = B_ * S_;                              // 4096 rows
constexpr size_t HS_ELEMS = (size_t)B_ * H_ * S_ * DP_;  // head-split tensor elems
constexpr size_t OUT_ELEMS = (size_t)M_ * D_;
constexpr size_t NROWS = (size_t)B_ * H_ * S_;           // attn row count (49152)
constexpr int NKT = 16;                                  // 128-key tiles per row
constexpr size_t PSTRIDE = (size_t)NKT * NROWS;          // pstat plane stride

typedef __bf16 bf16_t;
typedef bf16_t bf16x8 __attribute__((ext_vector_type(8)));
typedef float f32x4 __attribute__((ext_vector_type(4)));

__device__ __forceinline__ f32x4 mfma16(bf16x8 a, bf16x8 b, f32x4 c) {
  return __builtin_amdgcn_mfma_f32_16x16x32_bf16(a, b, c, 0, 0, 0);
}

__device__ __forceinline__ float truncbf(float x) {
  return __uint_as_float(__float_as_uint(x) & 0xFFFF0000u);
}
__device__ __forceinline__ uint32_t pack_hi2(float x, float y) {
  return (__float_as_uint(x) >> 16) | (__float_as_uint(y) & 0xFFFF0000u);
}
__device__ __forceinline__ uint32_t pack_lo2(float x, float y) {
  const float lx = x - truncbf(x);   // exact (Sterbenz)
  const float ly = y - truncbf(y);
  return (__float_as_uint(lx) >> 16) | (__float_as_uint(ly) & 0xFFFF0000u);
}
// 8 consecutive floats -> hi/lo planes, packed 2 bf16 per uint.
__device__ __forceinline__ void cvt8(const float4 a, const float4 b, uint4& H, uint4& L) {
  H.x = pack_hi2(a.x, a.y); H.y = pack_hi2(a.z, a.w);
  H.z = pack_hi2(b.x, b.y); H.w = pack_hi2(b.z, b.w);
  L.x = pack_lo2(a.x, a.y); L.y = pack_lo2(a.z, a.w);
  L.z = pack_lo2(b.x, b.y); L.w = pack_lo2(b.z, b.w);
}

// LDS tiles are [rows][64] bf16 (128B rows = 8 slots of 16B). Slot index is
// XOR-swizzled by (row&7): conflict-free ds_read_b128 fragment loads (T2/G4).
__device__ __forceinline__ bf16x8 ldfrag(const uint16_t (*T)[64], int row, int slot) {
  return *(const bf16x8*)&T[row][(slot ^ (row & 7)) << 3];
}

// ---------------------------------------------------------------------------
// Projections  Y = X @ W^T + bias.  X:[M,768], W:[768,768], both K-contiguous.
// 128x128 tile, BK=64, 256 threads = 4 waves (2x2 of 64x64), split-bf16 MFMA.
// MODE: 0 flat [M,768]; 1 headsplit [B,H,S,64];
//       2 headsplit-transposed split-bf16 planes Yh/Yl: [B,H,64,S] uint16.
// (verified through round 10)
// ---------------------------------------------------------------------------
template <int MODE>
__global__ __launch_bounds__(256) void xwt_mfma(const float* __restrict__ X,
                                                const float* __restrict__ W,
                                                const float* __restrict__ bias,
                                                float* __restrict__ Y,
                                                uint16_t* __restrict__ Yh,
                                                uint16_t* __restrict__ Yl) {
  __shared__ alignas(16) uint16_t Xh[128][64], Xl[128][64], Wh[128][64], Wl[128][64];
  const float* Xb = X + (size_t)blockIdx.x * 128 * D_;
  const float* Wb = W + (size_t)blockIdx.y * 128 * D_;
  const int t = threadIdx.x;
  const int lane = t & 63, wid = t >> 6;
  const int wm = (wid >> 1) * 64, wn = (wid & 1) * 64;
  const int r = lane & 15, g = lane >> 4;
  f32x4 acc[4][4] = {};
  for (int k0 = 0; k0 < D_; k0 += 64) {
    __syncthreads();  // protect previous iteration's fragment reads
#pragma unroll
    for (int i = 0; i < 8; ++i) {
      const int u = t + i * 256;
      const int tens = u >> 10;  // 0 = X, 1 = W (uniform per unrolled i)
      const int idx = u & 1023;
      const int row = idx >> 3, sl = idx & 7;
      const float* src = (tens ? Wb : Xb) + (size_t)row * D_ + k0 + sl * 8;
      const float4 a = *(const float4*)src;
      const float4 b = *(const float4*)(src + 4);
      uint4 H, L; cvt8(a, b, H, L);
      const int ps = (sl ^ (row & 7)) << 3;
      if (tens) { *(uint4*)&Wh[row][ps] = H; *(uint4*)&Wl[row][ps] = L; }
      else      { *(uint4*)&Xh[row][ps] = H; *(uint4*)&Xl[row][ps] = L; }
    }
    __syncthreads();
#pragma unroll
    for (int ks = 0; ks < 2; ++ks) {
      const int slot = ks * 4 + g;
      bf16x8 aH[4], aL[4], bH[4], bL[4];
#pragma unroll
      for (int mi = 0; mi < 4; ++mi) {
        const int row = wm + mi * 16 + r;
        aH[mi] = ldfrag(Xh, row, slot); aL[mi] = ldfrag(Xl, row, slot);
      }
#pragma unroll
      for (int ni = 0; ni < 4; ++ni) {
        const int row = wn + ni * 16 + r;
        bH[ni] = ldfrag(Wh, row, slot); bL[ni] = ldfrag(Wl, row, slot);
      }
#pragma unroll
      for (int mi = 0; mi < 4; ++mi)
#pragma unroll
        for (int ni = 0; ni < 4; ++ni) {
          acc[mi][ni] = mfma16(aH[mi], bH[ni], acc[mi][ni]);
          acc[mi][ni] = mfma16(aH[mi], bL[ni], acc[mi][ni]);
          acc[mi][ni] = mfma16(aL[mi], bH[ni], acc[mi][ni]);
        }
    }
  }
  const int m0 = blockIdx.x * 128 + wm;
  const int n0 = blockIdx.y * 128 + wn;
#pragma unroll
  for (int mi = 0; mi < 4; ++mi) {
    const int rowb = m0 + mi * 16 + 4 * g;  // + j
#pragma unroll
    for (int ni = 0; ni < 4; ++ni) {
      const int col = n0 + ni * 16 + r;
      const float bv = bias[col];
      if (MODE == 0) {
        float* dst = Y + (size_t)rowb * D_ + col;
#pragma unroll
        for (int j = 0; j < 4; ++j) dst[(size_t)j * D_] = acc[mi][ni][j] + bv;
      } else if (MODE == 1) {
        const int h = col >> 6, d = col & 63;
#pragma unroll
        for (int j = 0; j < 4; ++j) {
          const int m = rowb + j;
          const int b = m >> 11, s = m & (S_ - 1);
          Y[(((size_t)b * H_ + h) * S_ + s) * DP_ + d] = acc[mi][ni][j] + bv;
        }
      } else {  // MODE 2: split-bf16 Vt planes [B,H,64,S], 4 consecutive s
        const int h = col >> 6, d = col & 63;
        const int b = rowb >> 11, s = rowb & (S_ - 1);
        const float o0 = acc[mi][ni][0] + bv, o1 = acc[mi][ni][1] + bv;
        const float o2 = acc[mi][ni][2] + bv, o3 = acc[mi][ni][3] + bv;
        uint2 hi, lo;
        hi.x = pack_hi2(o0, o1); hi.y = pack_hi2(o2, o3);
        lo.x = pack_lo2(o0, o1); lo.y = pack_lo2(o2, o3);
        const size_t off = (((size_t)b * H_ + h) * DP_ + d) * S_ + s;
        *(uint2*)(Yh + off) = hi;
        *(uint2*)(Yl + off) = lo;
      }
    }
  }
}

// ---------------------------------------------------------------------------
// scores_tile: grid (qtile=16, ktile=16, bh=24) — 6144 blocks. (verified)
// Raw masked/scaled 128x128 score tile -> attn buffer; per-row partial
// (max,sum) over this tile's keys -> pstat[ktile].
// ---------------------------------------------------------------------------
__global__ __launch_bounds__(256) void scores_tile(const float* __restrict__ Q,
                                                   const float* __restrict__ K,
                                                   const int* __restrict__ mask,
                                                   float* __restrict__ P,
                                                   float* __restrict__ pstat) {
  __shared__ alignas(16) uint16_t Qh[128][64], Ql[128][64], Kh[128][64], Kl[128][64];
  __shared__ float mred[2][2][64], sred[2][2][64];
  const int bh = blockIdx.z;
  const int qbase = blockIdx.x * 128, kbase = blockIdx.y * 128;
  const float* Qb = Q + ((size_t)bh * S_ + qbase) * DP_;
  const float* Kb = K + ((size_t)bh * S_ + kbase) * DP_;
  float* Pb = P + ((size_t)bh * S_ + qbase) * S_ + kbase;
  const int* mb = mask + (size_t)(bh / H_) * S_ + kbase;
  const int t = threadIdx.x;
#pragma unroll
  for (int i = 0; i < 8; ++i) {
    const int u = t + i * 256;
    const int tens = u >> 10;  // 0 = Q, 1 = K
    const int idx = u & 1023;
    const int row = idx >> 3, sl = idx & 7;
    const float* src = (tens ? Kb : Qb) + (size_t)row * DP_ + sl * 8;
    const float4 a = *(const float4*)src;
    const float4 b = *(const float4*)(src + 4);
    uint4 H, L; cvt8(a, b, H, L);
    const int ps = (sl ^ (row & 7)) << 3;
    if (tens) { *(uint4*)&Kh[row][ps] = H; *(uint4*)&Kl[row][ps] = L; }
    else      { *(uint4*)&Qh[row][ps] = H; *(uint4*)&Ql[row][ps] = L; }
  }
  __syncthreads();
  const int lane = t & 63, wid = t >> 6;
  const int wm = (wid >> 1) * 64, wn = (wid & 1) * 64;
  const int r = lane & 15, g = lane >> 4;
  f32x4 acc[4][4] = {};
#pragma unroll
  for (int ks = 0; ks < 2; ++ks) {
    const int slot = ks * 4 + g;
    bf16x8 aH[4], aL[4], bH[4], bL[4];
#pragma unroll
    for (int mi = 0; mi < 4; ++mi) {
      const int row = wm + mi * 16 + r;
      aH[mi] = ldfrag(Qh, row, slot); aL[mi] = ldfrag(Ql, row, slot);
    }
#pragma unroll
    for (int ni = 0; ni < 4; ++ni) {
      const int row = wn + ni * 16 + r;
      bH[ni] = ldfrag(Kh, row, slot); bL[ni] = ldfrag(Kl, row, slot);
    }
#pragma unroll
    for (int mi = 0; mi < 4; ++mi)
#pragma unroll
      for (int ni = 0; ni < 4; ++ni) {
        acc[mi][ni] = mfma16(aH[mi], bH[ni], acc[mi][ni]);
        acc[mi][ni] = mfma16(aH[mi], bL[ni], acc[mi][ni]);
        acc[mi][ni] = mfma16(aL[mi], bH[ni], acc[mi][ni]);
      }
  }
  // mask + scale + write raw + per-(row, this 128-key tile) partial stats
  int msk[4];
#pragma unroll
  for (int ni = 0; ni < 4; ++ni) msk[ni] = mb[wn + ni * 16 + r];
  float m_[4][4], s_[4][4];
#pragma unroll
  for (int mi = 0; mi < 4; ++mi) {
    float tv[4][4];
#pragma unroll
    for (int ni = 0; ni < 4; ++ni)
#pragma unroll
      for (int j = 0; j < 4; ++j) {
        const float sv = msk[ni] ? acc[mi][ni][j] * 0.125f : -1e30f;
        tv[ni][j] = sv;
        Pb[(size_t)(wm + mi * 16 + 4 * g + j) * S_ + wn + ni * 16 + r] = sv;
      }
#pragma unroll
    for (int j = 0; j < 4; ++j) {
      // tile-row max across this thread's 4 values, then 16 r-lanes
      float M = fmaxf(fmaxf(tv[0][j], tv[1][j]), fmaxf(tv[2][j], tv[3][j]));
#pragma unroll
      for (int off = 1; off < 16; off <<= 1) M = fmaxf(M, __shfl_xor(M, off));
      // one exp pass vs tile max, then sum across r-lanes
      float ssum = 0.f;
#pragma unroll
      for (int ni = 0; ni < 4; ++ni)
        ssum += (tv[ni][j] <= -1e29f) ? 0.f : __expf(tv[ni][j] - M);
#pragma unroll
      for (int off = 1; off < 16; off <<= 1) ssum += __shfl_xor(ssum, off);
      m_[mi][j] = M; s_[mi][j] = ssum;
    }
  }
  // combine the two wn-half waves via LDS, then write this k-tile's partials
  if (r == 0) {
#pragma unroll
    for (int mi = 0; mi < 4; ++mi)
#pragma unroll
      for (int j = 0; j < 4; ++j) {
        mred[wid >> 1][wid & 1][mi * 16 + 4 * g + j] = m_[mi][j];
        sred[wid >> 1][wid & 1][mi * 16 + 4 * g + j] = s_[mi][j];
      }
  }
  __syncthreads();
  if (t < 128) {
    const int half = t >> 6, rowid = t & 63;
    const float m0 = mred[half][0][rowid], m1 = mred[half][1][rowid];
    const float s0 = sred[half][0][rowid], s1 = sred[half][1][rowid];
    const float mn = fmaxf(m0, m1);
    const float s = s0 * __expf(m0 - mn) + s1 * __expf(m1 - mn);
    const size_t row = (size_t)bh * S_ + qbase + half * 64 + rowid;
    pstat[(size_t)blockIdx.y * NROWS + row] = mn;
    pstat[PSTRIDE + (size_t)blockIdx.y * NROWS + row] = s;
  }
}

// ---------------------------------------------------------------------------
// stat_combine: one thread per q-row; fold 16 per-tile partials -> (m, 1/sum).
// (verified)
// ---------------------------------------------------------------------------
__global__ __launch_bounds__(256) void stat_combine(const float* __restrict__ pstat,
                                                    float* __restrict__ mstat) {
  const size_t row = (size_t)blockIdx.x * 256 + threadIdx.x;  // NROWS = 192*256
  float m = pstat[row], s = pstat[PSTRIDE + row];
#pragma unroll
  for (int kt = 1; kt < NKT; ++kt) {
    const float pm = pstat[(size_t)kt * NROWS + row];
    const float ps = pstat[PSTRIDE + (size_t)kt * NROWS + row];
    const float mn = fmaxf(m, pm);
    s = s * __expf(m - mn) + ps * __expf(pm - mn);
    m = mn;
  }
  mstat[row] = m;
  mstat[NROWS + row] = 1.0f / s;
}

// ---------------------------------------------------------------------------
// ctx_fused: grid (S/64=32, B*H=24) = 768 blocks, 4 waves. Round-1 ctx_mfma
// structure (verified fast): per 64-key tile, stage P 64x64 f32 with BLOCK-
// COALESCED loads -- applying p = exp(s-m)*inv inline, writing normalized
// attn back in place -- convert to split-bf16 LDS; stage bf16 V planes by
// plain uint4 copies; MFMA. Each wave: 16 q-rows x 64 d.
// ---------------------------------------------------------------------------
__global__ __launch_bounds__(256) void ctx_fused(float* __restrict__ P,
                                                 const uint16_t* __restrict__ Vth,
                                                 const uint16_t* __restrict__ Vtl,
                                                 const float* __restrict__ mstat,
                                                 float* __restrict__ C) {
  __shared__ alignas(16) uint16_t Ph[64][64], Pl[64][64], Vh[64][64], Vl[64][64];
  __shared__ float mrow[64], irow[64];
  const int bh = blockIdx.y;
  const int b = bh / H_, h = bh % H_;
  const int qbase = blockIdx.x * 64;
  float* Pb = P + ((size_t)bh * S_ + qbase) * S_;
  const uint16_t* vbh = Vth + (size_t)bh * DP_ * S_;
  const uint16_t* vbl = Vtl + (size_t)bh * DP_ * S_;
  const int t = threadIdx.x;
  if (t < 64) {
    const size_t qg = (size_t)bh * S_ + qbase + t;
    mrow[t] = mstat[qg];
    irow[t] = mstat[NROWS + qg];
  }
  const int lane = t & 63, wid = t >> 6;
  const int r = lane & 15, g = lane >> 4;
  f32x4 acc[4] = {};
  for (int kt = 0; kt < 32; ++kt) {
    __syncthreads();  // covers mrow/irow on iter 0, prev-tile LDS reads after
    // stage P: 64 rows x 64 keys, 512 chunks of 8 floats (coalesced),
    // normalize inline, write attn back in place, split-bf16 into LDS.
#pragma unroll
    for (int i = 0; i < 2; ++i) {
      const int u = t + i * 256;
      const int row = u >> 3, sl = u & 7;
      float* src = Pb + (size_t)row * S_ + kt * 64 + sl * 8;
      float4 p0 = *(const float4*)src;
      float4 p1 = *(const float4*)(src + 4);
      const float mq = mrow[row], iv = irow[row];
      p0.x = __expf(p0.x - mq) * iv; p0.y = __expf(p0.y - mq) * iv;
      p0.z = __expf(p0.z - mq) * iv; p0.w = __expf(p0.w - mq) * iv;
      p1.x = __expf(p1.x - mq) * iv; p1.y = __expf(p1.y - mq) * iv;
      p1.z = __expf(p1.z - mq) * iv; p1.w = __expf(p1.w - mq) * iv;
      *(float4*)src = p0;             // normalized attn, in place
      *(float4*)(src + 4) = p1;
      uint4 H, L; cvt8(p0, p1, H, L);
      const int ps = (sl ^ (row & 7)) << 3;
      *(uint4*)&Ph[row][ps] = H; *(uint4*)&Pl[row][ps] = L;
    }
    // stage V planes: 64 d-rows x 64 keys bf16, 512 chunks of 16B (coalesced)
#pragma unroll
    for (int i = 0; i < 2; ++i) {
      const int u = t + i * 256;
      const int row = u >> 3, sl = u & 7;
      const size_t off = (size_t)row * S_ + kt * 64 + sl * 8;
      const uint4 hv = *(const uint4*)(vbh + off);
      const uint4 lv = *(const uint4*)(vbl + off);
      const int ps = (sl ^ (row & 7)) << 3;
      *(uint4*)&Vh[row][ps] = hv; *(uint4*)&Vl[row][ps] = lv;
    }
    __syncthreads();
#pragma unroll
    for (int ks = 0; ks < 2; ++ks) {
      const int slot = ks * 4 + g;
      const int arow = wid * 16 + r;
      const bf16x8 aH = ldfrag(Ph, arow, slot);
      const bf16x8 aL = ldfrag(Pl, arow, slot);
#pragma unroll
      for (int ni = 0; ni < 4; ++ni) {
        const int drow = ni * 16 + r;
        const bf16x8 bH = ldfrag(Vh, drow, slot);
        const bf16x8 bL = ldfrag(Vl, drow, slot);
        acc[ni] = mfma16(aH, bH, acc[ni]);
        acc[ni] = mfma16(aH, bL, acc[ni]);
        acc[ni] = mfma16(aL, bH, acc[ni]);
      }
    }
  }
  // epilogue: ctx concat layout C[b][s][h*64+d] (round-1 verified mapping)
  const int s0 = qbase + wid * 16 + 4 * g;
#pragma unroll
  for (int ni = 0; ni < 4; ++ni) {
    const int d = ni * 16 + r;
#pragma unroll
    for (int j = 0; j < 4; ++j)
      C[(size_t)(b * S_ + s0 + j) * D_ + h * DP_ + d] = acc[ni][j];
  }
}

extern "C" void kernel_launch(void* const* d_in, const int* in_sizes, int n_in,
                              void* d_out, int out_size, void* d_ws, size_t ws_size,
                              hipStream_t stream) {
  (void)in_sizes; (void)n_in; (void)out_size; (void)ws_size;
  const float* q = (const float*)d_in[0];
  const float* k = (const float*)d_in[1];
  const float* v = (const float*)d_in[2];
  const int* mask = (const int*)d_in[3];
  const float* wq_w = (const float*)d_in[4];
  const float* wq_b = (const float*)d_in[5];
  const float* wk_w = (const float*)d_in[6];
  const float* wk_b = (const float*)d_in[7];
  const float* wv_w = (const float*)d_in[8];
  const float* wv_b = (const float*)d_in[9];
  const float* wo_w = (const float*)d_in[10];
  const float* wo_b = (const float*)d_in[11];

  float* out = (float*)d_out;
  float* attn = (float*)d_out + OUT_ELEMS;

  float* qh = (float*)d_ws;                       // [B,H,S,64] f32
  float* khd = qh + HS_ELEMS;                     // [B,H,S,64] f32
  uint16_t* vth = (uint16_t*)(khd + HS_ELEMS);    // [B,H,64,S] bf16 hi
  uint16_t* vtl = vth + HS_ELEMS;                 // [B,H,64,S] bf16 lo
  float* ctx = (float*)(vtl + HS_ELEMS);          // [B,S,768] concat layout
  float* mstat = ctx + OUT_ELEMS;                 // [2][NROWS] rowmax, 1/rowsum
  float* pstat = mstat + 2 * NROWS;               // [2][16][NROWS] partials

  const dim3 gproj(M_ / 128, D_ / 128);
  xwt_mfma<1><<<gproj, 256, 0, stream>>>(q, wq_w, wq_b, qh, nullptr, nullptr);
  xwt_mfma<1><<<gproj, 256, 0, stream>>>(k, wk_w, wk_b, khd, nullptr, nullptr);
  xwt_mfma<2><<<gproj, 256, 0, stream>>>(v, wv_w, wv_b, nullptr, vth, vtl);

  const dim3 gsc(S_ / 128, S_ / 128, B_ * H_);
  scores_tile<<<gsc, 256, 0, stream>>>(qh, khd, mask, attn, pstat);

  stat_combine<<<dim3(NROWS / 256), 256, 0, stream>>>(pstat, mstat);

  const dim3 gctx(S_ / 64, B_ * H_);
  ctx_fused<<<gctx, 256, 0, stream>>>(attn, vth, vtl, mstat, ctx);

  xwt_mfma<0><<<gproj, 256, 0, stream>>>(ctx, wo_w, wo_b, out, nullptr, nullptr);
}

// Round 13
// 882.286 us; speedup vs baseline: 1.3306x; 1.0668x over previous
//
#include <hip/hip_runtime.h>
#include <math.h>
#include <stdint.h>

// MultiHeadAttention: B=2,S=2048,D=768,H=12,depth=64
// out = (softmax(mask(QK^T/8)) V) Wo^T + bo ; also returns attn itself.
// d_out = [out (B*S*D) | attn (B*H*S*S)] fp32.
//
// Round 12 design (resubmitted after broker timeout): attn matrix touches
// HBM once (write) instead of 3x.
//  - stats_tile: verified scores_tile MINUS the raw-score write (pure
//    compute; per-ktile partial (max,sum) -> pstat).
//  - stat_combine: verified.
//  - attn_pv: recomputes QK^T (bit-identical MFMA path), normalizes with
//    mstat, writes attn ONCE, parks P in padded f32 LDS, PV-MFMAs against
//    verified bf16 V planes, writes ctx. Replaces scores-write + ctx_fused.
constexpr int B_ = 2, S_ = 2048, D_ = 768, H_ = 12, DP_ = 64;
constexpr int M_ = B_ * S_;                              // 4096 rows
constexpr size_t HS_ELEMS = (size_t)B_ * H_ * S_ * DP_;  // head-split tensor elems
constexpr size_t OUT_ELEMS = (size_t)M_ * D_;
constexpr size_t NROWS = (size_t)B_ * H_ * S_;           // attn row count (49152)
constexpr int NKT = 16;                                  // 128-key tiles per row
constexpr size_t PSTRIDE = (size_t)NKT * NROWS;          // pstat plane stride

typedef __bf16 bf16_t;
typedef bf16_t bf16x8 __attribute__((ext_vector_type(8)));
typedef float f32x4 __attribute__((ext_vector_type(4)));

__device__ __forceinline__ f32x4 mfma16(bf16x8 a, bf16x8 b, f32x4 c) {
  return __builtin_amdgcn_mfma_f32_16x16x32_bf16(a, b, c, 0, 0, 0);
}

__device__ __forceinline__ float truncbf(float x) {
  return __uint_as_float(__float_as_uint(x) & 0xFFFF0000u);
}
__device__ __forceinline__ uint32_t pack_hi2(float x, float y) {
  return (__float_as_uint(x) >> 16) | (__float_as_uint(y) & 0xFFFF0000u);
}
__device__ __forceinline__ uint32_t pack_lo2(float x, float y) {
  const float lx = x - truncbf(x);   // exact (Sterbenz)
  const float ly = y - truncbf(y);
  return (__float_as_uint(lx) >> 16) | (__float_as_uint(ly) & 0xFFFF0000u);
}
// 8 consecutive floats -> hi/lo planes, packed 2 bf16 per uint.
__device__ __forceinline__ void cvt8(const float4 a, const float4 b, uint4& H, uint4& L) {
  H.x = pack_hi2(a.x, a.y); H.y = pack_hi2(a.z, a.w);
  H.z = pack_hi2(b.x, b.y); H.w = pack_hi2(b.z, b.w);
  L.x = pack_lo2(a.x, a.y); L.y = pack_lo2(a.z, a.w);
  L.z = pack_lo2(b.x, b.y); L.w = pack_lo2(b.z, b.w);
}

// LDS tiles are [rows][64] bf16 (128B rows = 8 slots of 16B). Slot index is
// XOR-swizzled by (row&7): conflict-free ds_read_b128 fragment loads (T2/G4).
__device__ __forceinline__ bf16x8 ldfrag(const uint16_t (*T)[64], int row, int slot) {
  return *(const bf16x8*)&T[row][(slot ^ (row & 7)) << 3];
}

// ---------------------------------------------------------------------------
// Projections  Y = X @ W^T + bias.  (verified through round 11)
// MODE: 0 flat [M,768]; 1 headsplit [B,H,S,64];
//       2 headsplit-transposed split-bf16 planes Yh/Yl: [B,H,64,S] uint16.
// ---------------------------------------------------------------------------
template <int MODE>
__global__ __launch_bounds__(256) void xwt_mfma(const float* __restrict__ X,
                                                const float* __restrict__ W,
                                                const float* __restrict__ bias,
                                                float* __restrict__ Y,
                                                uint16_t* __restrict__ Yh,
                                                uint16_t* __restrict__ Yl) {
  __shared__ alignas(16) uint16_t Xh[128][64], Xl[128][64], Wh[128][64], Wl[128][64];
  const float* Xb = X + (size_t)blockIdx.x * 128 * D_;
  const float* Wb = W + (size_t)blockIdx.y * 128 * D_;
  const int t = threadIdx.x;
  const int lane = t & 63, wid = t >> 6;
  const int wm = (wid >> 1) * 64, wn = (wid & 1) * 64;
  const int r = lane & 15, g = lane >> 4;
  f32x4 acc[4][4] = {};
  for (int k0 = 0; k0 < D_; k0 += 64) {
    __syncthreads();  // protect previous iteration's fragment reads
#pragma unroll
    for (int i = 0; i < 8; ++i) {
      const int u = t + i * 256;
      const int tens = u >> 10;  // 0 = X, 1 = W (uniform per unrolled i)
      const int idx = u & 1023;
      const int row = idx >> 3, sl = idx & 7;
      const float* src = (tens ? Wb : Xb) + (size_t)row * D_ + k0 + sl * 8;
      const float4 a = *(const float4*)src;
      const float4 b = *(const float4*)(src + 4);
      uint4 H, L; cvt8(a, b, H, L);
      const int ps = (sl ^ (row & 7)) << 3;
      if (tens) { *(uint4*)&Wh[row][ps] = H; *(uint4*)&Wl[row][ps] = L; }
      else      { *(uint4*)&Xh[row][ps] = H; *(uint4*)&Xl[row][ps] = L; }
    }
    __syncthreads();
#pragma unroll
    for (int ks = 0; ks < 2; ++ks) {
      const int slot = ks * 4 + g;
      bf16x8 aH[4], aL[4], bH[4], bL[4];
#pragma unroll
      for (int mi = 0; mi < 4; ++mi) {
        const int row = wm + mi * 16 + r;
        aH[mi] = ldfrag(Xh, row, slot); aL[mi] = ldfrag(Xl, row, slot);
      }
#pragma unroll
      for (int ni = 0; ni < 4; ++ni) {
        const int row = wn + ni * 16 + r;
        bH[ni] = ldfrag(Wh, row, slot); bL[ni] = ldfrag(Wl, row, slot);
      }
#pragma unroll
      for (int mi = 0; mi < 4; ++mi)
#pragma unroll
        for (int ni = 0; ni < 4; ++ni) {
          acc[mi][ni] = mfma16(aH[mi], bH[ni], acc[mi][ni]);
          acc[mi][ni] = mfma16(aH[mi], bL[ni], acc[mi][ni]);
          acc[mi][ni] = mfma16(aL[mi], bH[ni], acc[mi][ni]);
        }
    }
  }
  const int m0 = blockIdx.x * 128 + wm;
  const int n0 = blockIdx.y * 128 + wn;
#pragma unroll
  for (int mi = 0; mi < 4; ++mi) {
    const int rowb = m0 + mi * 16 + 4 * g;  // + j
#pragma unroll
    for (int ni = 0; ni < 4; ++ni) {
      const int col = n0 + ni * 16 + r;
      const float bv = bias[col];
      if (MODE == 0) {
        float* dst = Y + (size_t)rowb * D_ + col;
#pragma unroll
        for (int j = 0; j < 4; ++j) dst[(size_t)j * D_] = acc[mi][ni][j] + bv;
      } else if (MODE == 1) {
        const int h = col >> 6, d = col & 63;
#pragma unroll
        for (int j = 0; j < 4; ++j) {
          const int m = rowb + j;
          const int b = m >> 11, s = m & (S_ - 1);
          Y[(((size_t)b * H_ + h) * S_ + s) * DP_ + d] = acc[mi][ni][j] + bv;
        }
      } else {  // MODE 2: split-bf16 Vt planes [B,H,64,S], 4 consecutive s
        const int h = col >> 6, d = col & 63;
        const int b = rowb >> 11, s = rowb & (S_ - 1);
        const float o0 = acc[mi][ni][0] + bv, o1 = acc[mi][ni][1] + bv;
        const float o2 = acc[mi][ni][2] + bv, o3 = acc[mi][ni][3] + bv;
        uint2 hi, lo;
        hi.x = pack_hi2(o0, o1); hi.y = pack_hi2(o2, o3);
        lo.x = pack_lo2(o0, o1); lo.y = pack_lo2(o2, o3);
        const size_t off = (((size_t)b * H_ + h) * DP_ + d) * S_ + s;
        *(uint2*)(Yh + off) = hi;
        *(uint2*)(Yl + off) = lo;
      }
    }
  }
}

// ---------------------------------------------------------------------------
// stats_tile: verified scores_tile structure MINUS the raw-score write.
// grid (qtile=16, ktile=16, bh=24). Per-row partial (max,sum) -> pstat.
// ---------------------------------------------------------------------------
__global__ __launch_bounds__(256) void stats_tile(const float* __restrict__ Q,
                                                  const float* __restrict__ K,
                                                  const int* __restrict__ mask,
                                                  float* __restrict__ pstat) {
  __shared__ alignas(16) uint16_t Qh[128][64], Ql[128][64], Kh[128][64], Kl[128][64];
  __shared__ float mred[2][2][64], sred[2][2][64];
  const int bh = blockIdx.z;
  const int qbase = blockIdx.x * 128, kbase = blockIdx.y * 128;
  const float* Qb = Q + ((size_t)bh * S_ + qbase) * DP_;
  const float* Kb = K + ((size_t)bh * S_ + kbase) * DP_;
  const int* mb = mask + (size_t)(bh / H_) * S_ + kbase;
  const int t = threadIdx.x;
#pragma unroll
  for (int i = 0; i < 8; ++i) {
    const int u = t + i * 256;
    const int tens = u >> 10;  // 0 = Q, 1 = K
    const int idx = u & 1023;
    const int row = idx >> 3, sl = idx & 7;
    const float* src = (tens ? Kb : Qb) + (size_t)row * DP_ + sl * 8;
    const float4 a = *(const float4*)src;
    const float4 b = *(const float4*)(src + 4);
    uint4 H, L; cvt8(a, b, H, L);
    const int ps = (sl ^ (row & 7)) << 3;
    if (tens) { *(uint4*)&Kh[row][ps] = H; *(uint4*)&Kl[row][ps] = L; }
    else      { *(uint4*)&Qh[row][ps] = H; *(uint4*)&Ql[row][ps] = L; }
  }
  __syncthreads();
  const int lane = t & 63, wid = t >> 6;
  const int wm = (wid >> 1) * 64, wn = (wid & 1) * 64;
  const int r = lane & 15, g = lane >> 4;
  f32x4 acc[4][4] = {};
#pragma unroll
  for (int ks = 0; ks < 2; ++ks) {
    const int slot = ks * 4 + g;
    bf16x8 aH[4], aL[4], bH[4], bL[4];
#pragma unroll
    for (int mi = 0; mi < 4; ++mi) {
      const int row = wm + mi * 16 + r;
      aH[mi] = ldfrag(Qh, row, slot); aL[mi] = ldfrag(Ql, row, slot);
    }
#pragma unroll
    for (int ni = 0; ni < 4; ++ni) {
      const int row = wn + ni * 16 + r;
      bH[ni] = ldfrag(Kh, row, slot); bL[ni] = ldfrag(Kl, row, slot);
    }
#pragma unroll
    for (int mi = 0; mi < 4; ++mi)
#pragma unroll
      for (int ni = 0; ni < 4; ++ni) {
        acc[mi][ni] = mfma16(aH[mi], bH[ni], acc[mi][ni]);
        acc[mi][ni] = mfma16(aH[mi], bL[ni], acc[mi][ni]);
        acc[mi][ni] = mfma16(aL[mi], bH[ni], acc[mi][ni]);
      }
  }
  int msk[4];
#pragma unroll
  for (int ni = 0; ni < 4; ++ni) msk[ni] = mb[wn + ni * 16 + r];
  float m_[4][4], s_[4][4];
#pragma unroll
  for (int mi = 0; mi < 4; ++mi) {
    float tv[4][4];
#pragma unroll
    for (int ni = 0; ni < 4; ++ni)
#pragma unroll
      for (int j = 0; j < 4; ++j)
        tv[ni][j] = msk[ni] ? acc[mi][ni][j] * 0.125f : -1e30f;
#pragma unroll
    for (int j = 0; j < 4; ++j) {
      float M = fmaxf(fmaxf(tv[0][j], tv[1][j]), fmaxf(tv[2][j], tv[3][j]));
#pragma unroll
      for (int off = 1; off < 16; off <<= 1) M = fmaxf(M, __shfl_xor(M, off));
      float ssum = 0.f;
#pragma unroll
      for (int ni = 0; ni < 4; ++ni)
        ssum += (tv[ni][j] <= -1e29f) ? 0.f : __expf(tv[ni][j] - M);
#pragma unroll
      for (int off = 1; off < 16; off <<= 1) ssum += __shfl_xor(ssum, off);
      m_[mi][j] = M; s_[mi][j] = ssum;
    }
  }
  if (r == 0) {
#pragma unroll
    for (int mi = 0; mi < 4; ++mi)
#pragma unroll
      for (int j = 0; j < 4; ++j) {
        mred[wid >> 1][wid & 1][mi * 16 + 4 * g + j] = m_[mi][j];
        sred[wid >> 1][wid & 1][mi * 16 + 4 * g + j] = s_[mi][j];
      }
  }
  __syncthreads();
  if (t < 128) {
    const int half = t >> 6, rowid = t & 63;
    const float m0 = mred[half][0][rowid], m1 = mred[half][1][rowid];
    const float s0 = sred[half][0][rowid], s1 = sred[half][1][rowid];
    const float mn = fmaxf(m0, m1);
    const float s = s0 * __expf(m0 - mn) + s1 * __expf(m1 - mn);
    const size_t row = (size_t)bh * S_ + qbase + half * 64 + rowid;
    pstat[(size_t)blockIdx.y * NROWS + row] = mn;
    pstat[PSTRIDE + (size_t)blockIdx.y * NROWS + row] = s;
  }
}

// ---------------------------------------------------------------------------
// stat_combine: one thread per q-row; fold 16 per-tile partials -> (m, 1/sum).
// (verified)
// ---------------------------------------------------------------------------
__global__ __launch_bounds__(256) void stat_combine(const float* __restrict__ pstat,
                                                    float* __restrict__ mstat) {
  const size_t row = (size_t)blockIdx.x * 256 + threadIdx.x;  // NROWS = 192*256
  float m = pstat[row], s = pstat[PSTRIDE + row];
#pragma unroll
  for (int kt = 1; kt < NKT; ++kt) {
    const float pm = pstat[(size_t)kt * NROWS + row];
    const float ps = pstat[PSTRIDE + (size_t)kt * NROWS + row];
    const float mn = fmaxf(m, pm);
    s = s * __expf(m - mn) + ps * __expf(pm - mn);
    m = mn;
  }
  mstat[row] = m;
  mstat[NROWS + row] = 1.0f / s;
}

// ---------------------------------------------------------------------------
// attn_pv: grid (S/64=32, B*H=24) = 768 blocks, 4 waves, LDS ~50KB
// (3 blocks/CU). Per 64-key tile: stage K (verified cvt-staging) + V planes
// (verified copies); recompute QK^T (bit-identical to stats pass); normalize
// with mstat; write attn ONCE (coalesced per-row segments); park P in padded
// f32 LDS; read back as A-fragments; PV MFMA (verified pattern); ctx epilogue.
// ---------------------------------------------------------------------------
__global__ __launch_bounds__(256) void attn_pv(const float* __restrict__ Qf,
                                               const float* __restrict__ Kf,
                                               const uint16_t* __restrict__ Vth,
                                               const uint16_t* __restrict__ Vtl,
                                               const float* __restrict__ mstat,
                                               const int* __restrict__ mask,
                                               float* __restrict__ P,
                                               float* __restrict__ C) {
  __shared__ alignas(16) uint16_t Kh[64][64], Kl[64][64], Vh[64][64], Vl[64][64];
  __shared__ float Pt[64][68];  // padded f32 P tile (2-way max bank alias)
  __shared__ float mrow[64], irow[64];
  const int bh = blockIdx.y;
  const int b = bh / H_, h = bh % H_;
  const int qbase = blockIdx.x * 64;
  const float* Kb = Kf + (size_t)bh * S_ * DP_;
  const uint16_t* vbh = Vth + (size_t)bh * DP_ * S_;
  const uint16_t* vbl = Vtl + (size_t)bh * DP_ * S_;
  float* Pg = P + ((size_t)bh * S_ + qbase) * S_;
  const int* mb = mask + (size_t)b * S_;
  const int t = threadIdx.x;
  if (t < 64) {
    const size_t qg = (size_t)bh * S_ + qbase + t;
    mrow[t] = mstat[qg];
    irow[t] = mstat[NROWS + qg];
  }
  const int lane = t & 63, wid = t >> 6;
  const int r = lane & 15, g = lane >> 4;
  // Q fragments for this wave's 16 rows: load once, keep in registers.
  bf16x8 qH[2], qL[2];
  {
    const float* Qrow = Qf + ((size_t)bh * S_ + qbase + wid * 16 + r) * DP_;
#pragma unroll
    for (int ks = 0; ks < 2; ++ks) {
      const int slot = ks * 4 + g;
      const float4 a = *(const float4*)(Qrow + slot * 8);
      const float4 b2 = *(const float4*)(Qrow + slot * 8 + 4);
      uint4 H, L; cvt8(a, b2, H, L);
      qH[ks] = *(bf16x8*)&H; qL[ks] = *(bf16x8*)&L;
    }
  }
  f32x4 acc[4] = {};
  for (int kt = 0; kt < 32; ++kt) {
    __syncthreads();  // prev-iter LDS reads done; iter-0: mrow/irow visible
    // stage K tile (64 keys x 64 depth, f32 -> split bf16, verified pattern)
#pragma unroll
    for (int i = 0; i < 2; ++i) {
      const int u = t + i * 256;
      const int row = u >> 3, sl = u & 7;
      const float* src = Kb + (size_t)(kt * 64 + row) * DP_ + sl * 8;
      const float4 a = *(const float4*)src;
      const float4 b2 = *(const float4*)(src + 4);
      uint4 H, L; cvt8(a, b2, H, L);
      const int ps = (sl ^ (row & 7)) << 3;
      *(uint4*)&Kh[row][ps] = H; *(uint4*)&Kl[row][ps] = L;
    }
    // stage V planes (64 d-rows x 64 keys bf16, plain copies, verified)
#pragma unroll
    for (int i = 0; i < 2; ++i) {
      const int u = t + i * 256;
      const int row = u >> 3, sl = u & 7;
      const size_t off = (size_t)row * S_ + kt * 64 + sl * 8;
      const uint4 hv = *(const uint4*)(vbh + off);
      const uint4 lv = *(const uint4*)(vbl + off);
      const int ps = (sl ^ (row & 7)) << 3;
      *(uint4*)&Vh[row][ps] = hv; *(uint4*)&Vl[row][ps] = lv;
    }
    __syncthreads();
    // QK^T for this wave's 16 q-rows x 64 keys (bit-identical to stats pass)
    f32x4 s4[4] = {};
#pragma unroll
    for (int ks = 0; ks < 2; ++ks) {
      const int slot = ks * 4 + g;
#pragma unroll
      for (int ni = 0; ni < 4; ++ni) {
        const int row = ni * 16 + r;
        const bf16x8 bH = ldfrag(Kh, row, slot);
        const bf16x8 bL = ldfrag(Kl, row, slot);
        s4[ni] = mfma16(qH[ks], bH, s4[ni]);
        s4[ni] = mfma16(qH[ks], bL, s4[ni]);
        s4[ni] = mfma16(qL[ks], bH, s4[ni]);
      }
    }
    // normalize (C-layout: row = 4g+j local, col = ni*16+r), write attn once,
    // park P in LDS for the PV A-fragment read.
#pragma unroll
    for (int ni = 0; ni < 4; ++ni) {
      const int msk = mb[kt * 64 + ni * 16 + r];
#pragma unroll
      for (int j = 0; j < 4; ++j) {
        const int rl = wid * 16 + 4 * g + j;
        const float sv = msk ? s4[ni][j] * 0.125f : -1e30f;
        const float p = __expf(sv - mrow[rl]) * irow[rl];  // masked -> 0
        Pg[(size_t)rl * S_ + kt * 64 + ni * 16 + r] = p;
        Pt[rl][ni * 16 + r] = p;
      }
    }
    __syncthreads();  // P tile visible
    // PV: A-fragments from Pt (own wave's rows), B from V planes (verified)
#pragma unroll
    for (int ks = 0; ks < 2; ++ks) {
      const int slot = ks * 4 + g;
      const float4 a = *(const float4*)&Pt[wid * 16 + r][slot * 8];
      const float4 b2 = *(const float4*)&Pt[wid * 16 + r][slot * 8 + 4];
      uint4 H, L; cvt8(a, b2, H, L);
      const bf16x8 pH = *(bf16x8*)&H, pL = *(bf16x8*)&L;
#pragma unroll
      for (int ni = 0; ni < 4; ++ni) {
        const int drow = ni * 16 + r;
        const bf16x8 bH = ldfrag(Vh, drow, slot);
        const bf16x8 bL = ldfrag(Vl, drow, slot);
        acc[ni] = mfma16(pH, bH, acc[ni]);
        acc[ni] = mfma16(pH, bL, acc[ni]);
        acc[ni] = mfma16(pL, bH, acc[ni]);
      }
    }
  }
  // epilogue: ctx concat layout C[b][s][h*64+d] (verified mapping)
  const int s0 = qbase + wid * 16 + 4 * g;
#pragma unroll
  for (int ni = 0; ni < 4; ++ni) {
    const int d = ni * 16 + r;
#pragma unroll
    for (int j = 0; j < 4; ++j)
      C[(size_t)(b * S_ + s0 + j) * D_ + h * DP_ + d] = acc[ni][j];
  }
}

extern "C" void kernel_launch(void* const* d_in, const int* in_sizes, int n_in,
                              void* d_out, int out_size, void* d_ws, size_t ws_size,
                              hipStream_t stream) {
  (void)in_sizes; (void)n_in; (void)out_size; (void)ws_size;
  const float* q = (const float*)d_in[0];
  const float* k = (const float*)d_in[1];
  const float* v = (const float*)d_in[2];
  const int* mask = (const int*)d_in[3];
  const float* wq_w = (const float*)d_in[4];
  const float* wq_b = (const float*)d_in[5];
  const float* wk_w = (const float*)d_in[6];
  const float* wk_b = (const float*)d_in[7];
  const float* wv_w = (const float*)d_in[8];
  const float* wv_b = (const float*)d_in[9];
  const float* wo_w = (const float*)d_in[10];
  const float* wo_b = (const float*)d_in[11];

  float* out = (float*)d_out;
  float* attn = (float*)d_out + OUT_ELEMS;

  float* qh = (float*)d_ws;                       // [B,H,S,64] f32
  float* khd = qh + HS_ELEMS;                     // [B,H,S,64] f32
  uint16_t* vth = (uint16_t*)(khd + HS_ELEMS);    // [B,H,64,S] bf16 hi
  uint16_t* vtl = vth + HS_ELEMS;                 // [B,H,64,S] bf16 lo
  float* ctx = (float*)(vtl + HS_ELEMS);          // [B,S,768] concat layout
  float* mstat = ctx + OUT_ELEMS;                 // [2][NROWS] rowmax, 1/rowsum
  float* pstat = mstat + 2 * NROWS;               // [2][16][NROWS] partials

  const dim3 gproj(M_ / 128, D_ / 128);
  xwt_mfma<1><<<gproj, 256, 0, stream>>>(q, wq_w, wq_b, qh, nullptr, nullptr);
  xwt_mfma<1><<<gproj, 256, 0, stream>>>(k, wk_w, wk_b, khd, nullptr, nullptr);
  xwt_mfma<2><<<gproj, 256, 0, stream>>>(v, wv_w, wv_b, nullptr, vth, vtl);

  const dim3 gsc(S_ / 128, S_ / 128, B_ * H_);
  stats_tile<<<gsc, 256, 0, stream>>>(qh, khd, mask, pstat);

  stat_combine<<<dim3(NROWS / 256), 256, 0, stream>>>(pstat, mstat);

  const dim3 gpv(S_ / 64, B_ * H_);
  attn_pv<<<gpv, 256, 0, stream>>>(qh, khd, vth, vtl, mstat, mask, attn, ctx);

  xwt_mfma<0><<<gproj, 256, 0, stream>>>(ctx, wo_w, wo_b, out, nullptr, nullptr);
}